// Round 8
// baseline (344.117 us; speedup 1.0000x reference)
//
#include <hip/hip_runtime.h>
#include <hip/hip_bf16.h>

#define H 1024
#define T 2048
#define B 32
#define BM 128        // rows per block (t-tile)
#define NCOLT 4       // column tiles
#define BCOLS 256     // cols per block

typedef __attribute__((ext_vector_type(8))) __bf16 bf16x8;
typedef __attribute__((ext_vector_type(16))) float f32x16;
typedef __attribute__((ext_vector_type(8))) unsigned short u16x8;

__device__ __forceinline__ unsigned short f2bf(float f) {
    unsigned int x = __float_as_uint(f);
    x += 0x7fffu + ((x >> 16) & 1u);
    return (unsigned short)(x >> 16);
}

__device__ __forceinline__ float fast_tanh(float x) {
    float t = __expf(2.0f * x);
    return 1.0f - 2.0f * __builtin_amdgcn_rcpf(t + 1.0f);
}

// Pack W2 = W[:, H:2H] into bf16, layout Wp[kg][n][8] (kg = k>>3), 16B per (kg,n)
__global__ __launch_bounds__(256) void prep_w_kernel(const float* __restrict__ W,
                                                     unsigned short* __restrict__ Wp) {
    int gid = blockIdx.x * 256 + threadIdx.x;   // 131072 total
    int n = gid & (H - 1);
    int kg = gid >> 10;                          // 0..127
    const float* srcp = W + (size_t)n * (2 * H) + H + kg * 8;
    float4 f0 = *(const float4*)(srcp);
    float4 f1 = *(const float4*)(srcp + 4);
    u16x8 o;
    o[0] = f2bf(f0.x); o[1] = f2bf(f0.y); o[2] = f2bf(f0.z); o[3] = f2bf(f0.w);
    o[4] = f2bf(f1.x); o[5] = f2bf(f1.y); o[6] = f2bf(f1.z); o[7] = f2bf(f1.w);
    *(u16x8*)(Wp + (size_t)gid * 8) = o;
}

// enc fp32 -> bf16, tile-transposed: Ap[bt][kg][row], 16B unit per (kg,row).
// bt = b*16 + (t>>7), kg = k>>3 (0..127), row = t&127. Writes fully coalesced.
__global__ __launch_bounds__(256) void prep_enc_kernel(const float* __restrict__ enc,
                                                       unsigned short* __restrict__ Ap) {
    int gid = blockIdx.x * 256 + threadIdx.x;   // 8,388,608 total units
    int row = gid & 127;
    int kg = (gid >> 7) & 127;
    int bt = gid >> 14;                          // 0..511
    int b = bt >> 4, tile = bt & 15;
    const float* src = enc + ((size_t)b * T + tile * 128 + row) * H + kg * 8;
    float4 f0 = *(const float4*)(src);
    float4 f1 = *(const float4*)(src + 4);
    u16x8 o;
    o[0] = f2bf(f0.x); o[1] = f2bf(f0.y); o[2] = f2bf(f0.z); o[3] = f2bf(f0.w);
    o[4] = f2bf(f1.x); o[5] = f2bf(f1.y); o[6] = f2bf(f1.z); o[7] = f2bf(f1.w);
    *(u16x8*)(Ap + (size_t)gid * 8) = o;
}

// hp[b][h] = sum_d hidden[b][d] * W[h][d] + bias[h]   (fp32, exact part)
__global__ __launch_bounds__(128) void prep_hp_kernel(const float* __restrict__ hidden,
                                                      const float* __restrict__ W,
                                                      const float* __restrict__ bias,
                                                      float* __restrict__ hp) {
    int b = blockIdx.y;
    int h = blockIdx.x * 128 + threadIdx.x;
    const float* hid = hidden + (size_t)b * H;
    const float* wr = W + (size_t)h * (2 * H);
    float acc = 0.f;
    for (int d = 0; d < H; d += 4) {
        float4 wv = *(const float4*)(wr + d);
        float4 hv = *(const float4*)(hid + d);
        acc += wv.x * hv.x + wv.y * hv.y + wv.z * hv.z + wv.w * hv.w;
    }
    hp[(size_t)b * H + h] = acc + bias[h];
}

#define MFMA32(A, Bv, C) __builtin_amdgcn_mfma_f32_32x32x16_bf16(A, Bv, C, 0, 0, 0)

// Streaming energy kernel: NO LDS staging, NO K-loop barriers. Block = (128-row tile,
// 256-col tile, b), 8 waves as 2(row)x4(col); wave = 64 rows x 64 cols, acc = 64 AGPR.
// A and B both stream from global (A: bf16 tile-transposed Ap, L3-resident; B: Wp in L2)
// with depth-2 rolling register prefetch. Waves free-run -> pipes overlap via TLP.
__global__ __launch_bounds__(512, 4) void energy_kernel(const unsigned short* __restrict__ Ap,
                                                        const float* __restrict__ hp,
                                                        const float* __restrict__ vvec,
                                                        const unsigned short* __restrict__ Wp,
                                                        float* __restrict__ sc_part) {
    __shared__ float scpart[8][BM];   // 4 KB only

    const int tid = threadIdx.x;
    const int b = blockIdx.z;
    const int t0 = blockIdx.x * BM;
    const int c0 = blockIdx.y * BCOLS;
    const int wave = tid >> 6;
    const int lane = tid & 63;
    const int l31 = lane & 31;
    const int hi = lane >> 5;
    const int wr = wave >> 2;     // 0..1 row-half
    const int wc = wave & 3;      // 0..3 col-group

    const int bt = b * 16 + blockIdx.x;
    // A per-lane pointers: page (bt,kg=hi), rows wr*64+{l31, 32+l31}; step = 2 pages = 2048 ush
    const unsigned short* ap0 = Ap + ((size_t)bt * 128 + hi) * 1024 + (size_t)(wr * 64 + l31) * 8;
    const unsigned short* ap1 = ap0 + 32 * 8;
    // B per-lane pointer: col c0+wc*64+{l31,+32}, page kg=hi; step = 2 pages = H*16 ush
    const unsigned short* wp_base = Wp + (size_t)(c0 + wc * 64 + l31) * 8 + (size_t)hi * (H * 8);

    f32x16 acc00, acc01, acc10, acc11;
#pragma unroll
    for (int i = 0; i < 16; ++i) { acc00[i] = 0.f; acc01[i] = 0.f; acc10[i] = 0.f; acc11[i] = 0.f; }

    // ---- prologue: depth-2 rolling preload (it=0 -> *A regs, it=1 -> *B regs) ----
    bf16x8 aA0 = *(const bf16x8*)(ap0);
    bf16x8 aA1 = *(const bf16x8*)(ap1);
    bf16x8 bA0 = *(const bf16x8*)(wp_base);
    bf16x8 bA1 = *(const bf16x8*)(wp_base + 256);
    bf16x8 aB0 = *(const bf16x8*)(ap0 + 2048);
    bf16x8 aB1 = *(const bf16x8*)(ap1 + 2048);
    bf16x8 bB0 = *(const bf16x8*)(wp_base + (size_t)H * 16);
    bf16x8 bB1 = *(const bf16x8*)(wp_base + (size_t)H * 16 + 256);

    // Rolling invariant: at STEP(KI) of j, regs hold it = 4j+KI; reload it+2 into the
    // same slot. Guard PER-STEP (nit < 64) -- final steps 2,3 load during steps 0,1 (R5 lesson).
#define STEP(KI, AC0, AC1, BC0, BC1)                                           \
    {                                                                          \
        __builtin_amdgcn_s_setprio(1);                                         \
        acc00 = MFMA32(AC0, BC0, acc00);                                       \
        acc01 = MFMA32(AC0, BC1, acc01);                                       \
        acc10 = MFMA32(AC1, BC0, acc10);                                       \
        acc11 = MFMA32(AC1, BC1, acc11);                                       \
        __builtin_amdgcn_s_setprio(0);                                         \
        const int nit = j * 4 + (KI) + 2;                                      \
        if (nit < 64) {                                                        \
            AC0 = *(const bf16x8*)(ap0 + (size_t)nit * 2048);                  \
            AC1 = *(const bf16x8*)(ap1 + (size_t)nit * 2048);                  \
            const unsigned short* bp = wp_base + (size_t)nit * (H * 16);       \
            BC0 = *(const bf16x8*)(bp);                                        \
            BC1 = *(const bf16x8*)(bp + 256);                                  \
        }                                                                      \
    }

    for (int j = 0; j < 16; ++j) {
        STEP(0, aA0, aA1, bA0, bA1)
        STEP(1, aB0, aB1, bB0, bB1)
        STEP(2, aA0, aA1, bA0, bA1)
        STEP(3, aB0, aB1, bB0, bB1)
    }
#undef STEP

    // ---- fused epilogue: tanh + v-dot over this wave's 64 cols ----
    const size_t bH = (size_t)b * H;
    const int col0 = c0 + wc * 64 + l31;
    const int col1 = col0 + 32;
    const float hp0 = hp[bH + col0], hp1 = hp[bH + col1];
    const float v0 = vvec[col0], v1 = vvec[col1];
    float psc[2][16];
#pragma unroll
    for (int r = 0; r < 16; ++r) {
        psc[0][r] = v0 * fast_tanh(acc00[r] + hp0) + v1 * fast_tanh(acc01[r] + hp1);
        psc[1][r] = v0 * fast_tanh(acc10[r] + hp0) + v1 * fast_tanh(acc11[r] + hp1);
    }

#pragma unroll
    for (int rg = 0; rg < 2; ++rg)
#pragma unroll
        for (int r = 0; r < 16; ++r) {
            float s = psc[rg][r];
            s += __shfl_xor(s, 1);
            s += __shfl_xor(s, 2);
            s += __shfl_xor(s, 4);
            s += __shfl_xor(s, 8);
            s += __shfl_xor(s, 16);
            psc[rg][r] = s;
        }
    if (l31 == 0) {
#pragma unroll
        for (int rg = 0; rg < 2; ++rg)
#pragma unroll
            for (int r = 0; r < 16; ++r) {
                int m = wr * 64 + rg * 32 + (r & 3) + 8 * (r >> 2) + 4 * hi;
                scpart[wave][m] = psc[rg][r];
            }
    }
    __syncthreads();
    if (tid < BM) {
        const int wbase = (tid >> 6) * 4;   // the 4 waves holding this row-half
        float s = scpart[wbase][tid] + scpart[wbase + 1][tid] +
                  scpart[wbase + 2][tid] + scpart[wbase + 3][tid];
        sc_part[((size_t)blockIdx.y * B + b) * T + t0 + tid] = s;
    }
}

__global__ __launch_bounds__(256) void softmax_kernel(const float* __restrict__ sc,
                                                      float* __restrict__ out) {
    int b = blockIdx.x;
    int tid = threadIdx.x;
    int wave = tid >> 6, lane = tid & 63;
    const float* r0 = sc + (size_t)b * T;
    const float* r1 = sc + ((size_t)B + b) * T;
    const float* r2 = sc + ((size_t)2 * B + b) * T;
    const float* r3 = sc + ((size_t)3 * B + b) * T;
    float vals[8];
    float m = -1e30f;
#pragma unroll
    for (int i = 0; i < 8; ++i) {
        int idx = tid + 256 * i;
        vals[i] = (r0[idx] + r1[idx]) + (r2[idx] + r3[idx]);
        m = fmaxf(m, vals[i]);
    }
#pragma unroll
    for (int s = 1; s < 64; s <<= 1) m = fmaxf(m, __shfl_xor(m, s));
    __shared__ float red[4];
    __shared__ float red2[4];
    if (lane == 0) red[wave] = m;
    __syncthreads();
    m = fmaxf(fmaxf(red[0], red[1]), fmaxf(red[2], red[3]));
    float sum = 0.f;
#pragma unroll
    for (int i = 0; i < 8; ++i) { vals[i] = expf(vals[i] - m); sum += vals[i]; }
#pragma unroll
    for (int s = 1; s < 64; s <<= 1) sum += __shfl_xor(sum, s);
    if (lane == 0) red2[wave] = sum;
    __syncthreads();
    sum = red2[0] + red2[1] + red2[2] + red2[3];
    float inv = 1.0f / sum;
#pragma unroll
    for (int i = 0; i < 8; ++i) out[(size_t)b * T + tid + 256 * i] = vals[i] * inv;
}

extern "C" void kernel_launch(void* const* d_in, const int* in_sizes, int n_in,
                              void* d_out, int out_size, void* d_ws, size_t ws_size,
                              hipStream_t stream) {
    (void)in_sizes; (void)n_in; (void)out_size; (void)ws_size;
    const float* hidden = (const float*)d_in[0];   // [1,B,H]
    const float* enc    = (const float*)d_in[1];   // [B,T,H]
    const float* W      = (const float*)d_in[2];   // [H,2H]
    const float* bias   = (const float*)d_in[3];   // [H]
    const float* v      = (const float*)d_in[4];   // [H]
    float* out = (float*)d_out;                    // [B,1,T]

    unsigned short* Wp = (unsigned short*)d_ws;                               // 2 MB
    float* hp = (float*)((char*)d_ws + 2 * 1024 * 1024);                      // 128 KB
    float* sc = (float*)((char*)d_ws + 2 * 1024 * 1024 + 128 * 1024);         // 1 MB (4 partials)
    unsigned short* Ap = (unsigned short*)((char*)d_ws + 4 * 1024 * 1024);    // 128 MB

    prep_w_kernel<<<dim3(512), dim3(256), 0, stream>>>(W, Wp);
    prep_hp_kernel<<<dim3(8, B), dim3(128), 0, stream>>>(hidden, W, bias, hp);
    prep_enc_kernel<<<dim3(32768), dim3(256), 0, stream>>>(enc, Ap);
    energy_kernel<<<dim3(T / BM, NCOLT, B), dim3(512), 0, stream>>>(Ap, hp, v, Wp, sc);
    softmax_kernel<<<dim3(B), dim3(256), 0, stream>>>(sc, out);
}